// Round 1
// baseline (4104.506 us; speedup 1.0000x reference)
//
#include <hip/hip_runtime.h>
#include <hip/hip_bf16.h>
#include <math.h>

// RWKV-7 TimeMix, fp32 correctness-first baseline.
// B=4 T=2048 C=768 H=12 N=64, LAYER_ID=1 (v_first passes through).
//
// Pipeline:
//  r  = mix(x,lam_r) @ W_r^T
//  k0 = mix(x,lam_k) @ W_k^T
//  v0 = mix(x,lam_v) @ W_v^T
//  v  = v0 + (v_first - v0)*sigmoid(v_miu + (v0@v_A)@v_B)
//  decay = exp(-exp(-softplus(-(w_miu + tanh(mix(x,lam_w)@w_A)@w_B)) - 0.5))
//        = exp(-exp(-0.5)*sigmoid(w_miu + tanh(..)@w_B))
//  a  = sigmoid(a_miu + (mix(x,lam_a)@a_A)@a_B)
//  g  = sigmoid(mix(x,lam_g)@g_A) @ g_B
//  kk = normalize(k0*k_k) per head;  z=-kk; bb=kk*a;  k = k0*(1+(a-1)*k_a)
//  wkv7 recurrence -> y
//  y  = GN(y)*ln_w+ln_b + (sum_n r*k*r_k)*v ;  ym = y*g
//  out = ym @ W_o^T ; out2 = v_first
//
// Workspace layout (floats): 8 slots of B*T*C + 1 hidden of B*T*128 ≈ 196 MB.

#define B_  4
#define T_  2048
#define C_  768
#define H_  12
#define NH_ 64

static __device__ __forceinline__ float wave_sum64(float v) {
#pragma unroll
  for (int m = 32; m > 0; m >>= 1) v += __shfl_xor(v, m);
  return v;
}

// ---------------- GEMM ----------------
// C[M,N] = act( A'[M,K] @ B'[K,N] ), A' optionally time-mixed x, B either
// (K,N) row-major (BT=false) or (N,K) row-major i.e. A@W^T (BT=true).
enum { EPI_NONE = 0, EPI_TANH, EPI_WDECAY, EPI_SIGBIAS, EPI_SIGMOID, EPI_VMIX };

template <bool MIX, bool BT, int EPI>
__global__ __launch_bounds__(256) void gemm_k(
    const float* __restrict__ A, const float* __restrict__ Bm,
    float* __restrict__ Cc, int M, int N, int K,
    const float* __restrict__ lam, const float* __restrict__ bias,
    const float* __restrict__ ex1, const float* __restrict__ ex2) {
  __shared__ float As[64][20];
  __shared__ float Bs[64][20];
  const int tid = threadIdx.x;
  const int n0 = blockIdx.x * 64;
  const int m0 = blockIdx.y * 64;
  const int tx = tid & 15, ty = tid >> 4;

  float acc[4][4];
#pragma unroll
  for (int i = 0; i < 4; i++)
#pragma unroll
    for (int j = 0; j < 4; j++) acc[i][j] = 0.f;

  const int lm = tid >> 2;          // 0..63
  const int lk4 = (tid & 3) * 4;    // 0,4,8,12

  for (int k0 = 0; k0 < K; k0 += 16) {
    // ---- A tile (64 x 16) ----
    {
      const int gm = m0 + lm;
      const float* ap = A + (size_t)gm * K + k0 + lk4;
      float4 xa = *(const float4*)ap;
      if (MIX) {
        float4 xp = make_float4(0.f, 0.f, 0.f, 0.f);
        if ((gm % T_) != 0) xp = *(const float4*)(ap - K);
        const float4 l4 = *(const float4*)(lam + k0 + lk4);
        xa.x += (xp.x - xa.x) * l4.x;
        xa.y += (xp.y - xa.y) * l4.y;
        xa.z += (xp.z - xa.z) * l4.z;
        xa.w += (xp.w - xa.w) * l4.w;
      }
      *(float4*)&As[lm][lk4] = xa;
    }
    // ---- B tile (64 n x 16 k) ----
    if (BT) {
      const int gn = n0 + lm;
      const float4 bv = *(const float4*)(Bm + (size_t)gn * K + k0 + lk4);
      *(float4*)&Bs[lm][lk4] = bv;
    } else {
      const int kl = tid >> 4;        // 0..15
      const int nl = (tid & 15) * 4;  // 0..60
      const float4 bv = *(const float4*)(Bm + (size_t)(k0 + kl) * N + n0 + nl);
      Bs[nl + 0][kl] = bv.x;
      Bs[nl + 1][kl] = bv.y;
      Bs[nl + 2][kl] = bv.z;
      Bs[nl + 3][kl] = bv.w;
    }
    __syncthreads();

#pragma unroll
    for (int kb = 0; kb < 16; kb += 4) {
      float a4[4][4], b4[4][4];
#pragma unroll
      for (int i = 0; i < 4; i++) {
        const float4 t = *(const float4*)&As[ty * 4 + i][kb];
        a4[i][0] = t.x; a4[i][1] = t.y; a4[i][2] = t.z; a4[i][3] = t.w;
      }
#pragma unroll
      for (int j = 0; j < 4; j++) {
        const float4 t = *(const float4*)&Bs[tx * 4 + j][kb];
        b4[j][0] = t.x; b4[j][1] = t.y; b4[j][2] = t.z; b4[j][3] = t.w;
      }
#pragma unroll
      for (int u = 0; u < 4; u++)
#pragma unroll
        for (int i = 0; i < 4; i++)
#pragma unroll
          for (int j = 0; j < 4; j++)
            acc[i][j] = fmaf(a4[i][u], b4[j][u], acc[i][j]);
    }
    __syncthreads();
  }

  // ---- epilogue + store ----
#pragma unroll
  for (int i = 0; i < 4; i++) {
    const int gm = m0 + ty * 4 + i;
    float res[4];
#pragma unroll
    for (int j = 0; j < 4; j++) {
      const int n = n0 + tx * 4 + j;
      float val = acc[i][j];
      if (EPI == EPI_TANH) {
        val = tanhf(val);
      } else if (EPI == EPI_WDECAY) {
        const float u = bias[n] + val;
        const float sig = 1.f / (1.f + expf(-u));
        val = expf(-0.60653065971263342f * sig);
      } else if (EPI == EPI_SIGBIAS) {
        const float u = bias[n] + val;
        val = 1.f / (1.f + expf(-u));
      } else if (EPI == EPI_SIGMOID) {
        val = 1.f / (1.f + expf(-val));
      } else if (EPI == EPI_VMIX) {
        const float u = bias[n] + val;
        const float sg = 1.f / (1.f + expf(-u));
        const size_t off = (size_t)gm * N + n;
        const float v0v = ex1[off];
        const float vf = ex2[off];
        val = v0v + (vf - v0v) * sg;
      }
      res[j] = val;
    }
    *(float4*)(Cc + (size_t)gm * N + n0 + tx * 4) =
        make_float4(res[0], res[1], res[2], res[3]);
  }
}

// ---------------- kk prep ----------------
// per head-token: kk=k0*k_k; kkn=kk/max(||kk||,1e-12); z=-kkn; bb=kkn*a;
// k = k0*(1+(a-1)*k_a)   (in place over k0)
__global__ __launch_bounds__(256) void kkprep_k(
    const float* __restrict__ k0, const float* __restrict__ a,
    const float* __restrict__ k_k, const float* __restrict__ k_a,
    float* __restrict__ kout, float* __restrict__ z, float* __restrict__ bb) {
  const int wid = threadIdx.x >> 6;
  const int lane = threadIdx.x & 63;
  const size_t hid = (size_t)blockIdx.x * 4 + wid;  // (b*T+t)*H + h
  const int h = (int)(hid % H_);
  const size_t idx = hid * 64 + lane;
  const int c = h * 64 + lane;
  const float kv = k0[idx];
  const float av = a[idx];
  const float kk = kv * k_k[c];
  const float ss = wave_sum64(kk * kk);
  const float denom = fmaxf(sqrtf(ss), 1e-12f);
  const float kkn = kk / denom;
  z[idx] = -kkn;
  bb[idx] = kkn * av;
  kout[idx] = kv * (1.f + (av - 1.f) * k_a[c]);
}

// ---------------- WKV-7 recurrence ----------------
// grid: B*H*4 blocks of 64 threads. Block handles 16 rows of one (b,h).
// thread (ii=tid>>2, q=tid&3): row rg*16+ii, cols q*16..q*16+15.
__global__ __launch_bounds__(64) void wkv7_k(
    const float* __restrict__ rr, const float* __restrict__ dd,
    const float* __restrict__ kk, const float* __restrict__ vv,
    const float* __restrict__ zz, const float* __restrict__ bbv,
    float* __restrict__ yy) {
  const int blk = blockIdx.x;
  const int bh = blk >> 2, rg = blk & 3;
  const int b = bh / H_, h = bh % H_;
  const int tid = threadIdx.x;
  const int q = tid & 3;
  const int row = rg * 16 + (tid >> 2);
  const int cb = q * 16;

  float S[16];
#pragma unroll
  for (int c = 0; c < 16; c++) S[c] = 0.f;

  size_t base = ((size_t)b * T_) * C_ + h * 64;
  for (int t = 0; t < T_; t++, base += C_) {
    float w4[16], z4[16], b4[16], k4[16], r4[16];
#pragma unroll
    for (int u = 0; u < 4; u++) {
      float4 tv;
      tv = *(const float4*)(dd + base + cb + 4 * u);
      w4[4 * u] = tv.x; w4[4 * u + 1] = tv.y; w4[4 * u + 2] = tv.z; w4[4 * u + 3] = tv.w;
      tv = *(const float4*)(zz + base + cb + 4 * u);
      z4[4 * u] = tv.x; z4[4 * u + 1] = tv.y; z4[4 * u + 2] = tv.z; z4[4 * u + 3] = tv.w;
      tv = *(const float4*)(bbv + base + cb + 4 * u);
      b4[4 * u] = tv.x; b4[4 * u + 1] = tv.y; b4[4 * u + 2] = tv.z; b4[4 * u + 3] = tv.w;
      tv = *(const float4*)(kk + base + cb + 4 * u);
      k4[4 * u] = tv.x; k4[4 * u + 1] = tv.y; k4[4 * u + 2] = tv.z; k4[4 * u + 3] = tv.w;
      tv = *(const float4*)(rr + base + cb + 4 * u);
      r4[4 * u] = tv.x; r4[4 * u + 1] = tv.y; r4[4 * u + 2] = tv.z; r4[4 * u + 3] = tv.w;
    }
    const float vi = vv[base + row];

    float sa = 0.f;
#pragma unroll
    for (int c = 0; c < 16; c++) sa = fmaf(S[c], z4[c], sa);
    sa += __shfl_xor(sa, 1);
    sa += __shfl_xor(sa, 2);

    float yp = 0.f;
#pragma unroll
    for (int c = 0; c < 16; c++) {
      S[c] = fmaf(S[c], w4[c], fmaf(sa, b4[c], vi * k4[c]));
      yp = fmaf(S[c], r4[c], yp);
    }
    yp += __shfl_xor(yp, 1);
    yp += __shfl_xor(yp, 2);
    if (q == 0) yy[base + row] = yp;
  }
}

// ---------------- GroupNorm + r_k term + g gating ----------------
__global__ __launch_bounds__(256) void gn_k(
    const float* __restrict__ y, const float* __restrict__ r,
    const float* __restrict__ k, const float* __restrict__ v,
    const float* __restrict__ g, const float* __restrict__ r_k,
    const float* __restrict__ ln_w, const float* __restrict__ ln_b,
    float* __restrict__ ym) {
  const int wid = threadIdx.x >> 6;
  const int lane = threadIdx.x & 63;
  const size_t hid = (size_t)blockIdx.x * 4 + wid;
  const int h = (int)(hid % H_);
  const size_t idx = hid * 64 + lane;
  const int c = h * 64 + lane;

  const float yv = y[idx];
  const float mu = wave_sum64(yv) * (1.f / 64.f);
  const float sq = wave_sum64(yv * yv) * (1.f / 64.f);
  const float var = sq - mu * mu;
  float yn = (yv - mu) * rsqrtf(var + 0.00064f);
  yn = yn * ln_w[c] + ln_b[c];

  const float s = wave_sum64(r[idx] * k[idx] * r_k[c]);
  yn += s * v[idx];
  ym[idx] = yn * g[idx];
}

// ---------------- copy ----------------
__global__ __launch_bounds__(256) void copy4_k(const float4* __restrict__ src,
                                               float4* __restrict__ dst, int n4) {
  const int i = blockIdx.x * blockDim.x + threadIdx.x;
  if (i < n4) dst[i] = src[i];
}

// ---------------- host launcher ----------------
template <bool MIX, bool BT, int EPI>
static void launch_gemm(const float* A, const float* Bm, float* Cc, int M,
                        int N, int K, const float* lam, const float* bias,
                        const float* ex1, const float* ex2, hipStream_t s) {
  dim3 grid(N / 64, M / 64), blk(256);
  hipLaunchKernelGGL((gemm_k<MIX, BT, EPI>), grid, blk, 0, s, A, Bm, Cc, M, N,
                     K, lam, bias, ex1, ex2);
}

extern "C" void kernel_launch(void* const* d_in, const int* in_sizes, int n_in,
                              void* d_out, int out_size, void* d_ws,
                              size_t ws_size, hipStream_t stream) {
  const float* x       = (const float*)d_in[0];
  const float* v_first = (const float*)d_in[1];
  const float* lam_r   = (const float*)d_in[2];
  const float* lam_w   = (const float*)d_in[3];
  const float* lam_k   = (const float*)d_in[4];
  const float* lam_v   = (const float*)d_in[5];
  const float* lam_a   = (const float*)d_in[6];
  const float* lam_g   = (const float*)d_in[7];
  const float* w_miu   = (const float*)d_in[8];
  const float* w_A     = (const float*)d_in[9];
  const float* w_B     = (const float*)d_in[10];
  const float* a_miu   = (const float*)d_in[11];
  const float* a_A     = (const float*)d_in[12];
  const float* a_B     = (const float*)d_in[13];
  const float* v_miu   = (const float*)d_in[14];
  const float* v_A     = (const float*)d_in[15];
  const float* v_B     = (const float*)d_in[16];
  const float* g_A     = (const float*)d_in[17];
  const float* g_B     = (const float*)d_in[18];
  const float* k_k     = (const float*)d_in[19];
  const float* k_a     = (const float*)d_in[20];
  const float* r_k     = (const float*)d_in[21];
  const float* W_r     = (const float*)d_in[22];
  const float* W_k     = (const float*)d_in[23];
  const float* W_v     = (const float*)d_in[24];
  const float* W_o     = (const float*)d_in[25];
  const float* ln_w    = (const float*)d_in[26];
  const float* ln_b    = (const float*)d_in[27];

  const int M = B_ * T_;           // 8192
  const size_t S = (size_t)M * C_; // 6291456

  float* ws   = (float*)d_ws;
  float* r_   = ws + 0 * S;
  float* kbuf = ws + 1 * S;
  float* vbuf = ws + 2 * S;
  float* dec_ = ws + 3 * S;  // decay; reused as ym after recurrence
  float* a_   = ws + 4 * S;  // a; reused as y after kkprep
  float* g_   = ws + 5 * S;
  float* z_   = ws + 6 * S;
  float* bb_  = ws + 7 * S;
  float* h_   = ws + 8 * S;  // hidden, up to M*128
  float* out  = (float*)d_out;

  // big projections (fused time-mix on A load)
  launch_gemm<true, true, EPI_NONE>(x, W_r, r_, M, C_, C_, lam_r, nullptr, nullptr, nullptr, stream);
  launch_gemm<true, true, EPI_NONE>(x, W_k, kbuf, M, C_, C_, lam_k, nullptr, nullptr, nullptr, stream);
  launch_gemm<true, true, EPI_NONE>(x, W_v, vbuf, M, C_, C_, lam_v, nullptr, nullptr, nullptr, stream);

  // v low-rank residual gate (uses v0 = vbuf, writes vbuf in place)
  launch_gemm<false, false, EPI_NONE>(vbuf, v_A, h_, M, 64, C_, nullptr, nullptr, nullptr, nullptr, stream);
  launch_gemm<false, false, EPI_VMIX>(h_, v_B, vbuf, M, C_, 64, nullptr, v_miu, vbuf, v_first, stream);

  // decay path
  launch_gemm<true, false, EPI_TANH>(x, w_A, h_, M, 64, C_, lam_w, nullptr, nullptr, nullptr, stream);
  launch_gemm<false, false, EPI_WDECAY>(h_, w_B, dec_, M, C_, 64, nullptr, w_miu, nullptr, nullptr, stream);

  // a path
  launch_gemm<true, false, EPI_NONE>(x, a_A, h_, M, 64, C_, lam_a, nullptr, nullptr, nullptr, stream);
  launch_gemm<false, false, EPI_SIGBIAS>(h_, a_B, a_, M, C_, 64, nullptr, a_miu, nullptr, nullptr, stream);

  // g path
  launch_gemm<true, false, EPI_SIGMOID>(x, g_A, h_, M, 128, C_, lam_g, nullptr, nullptr, nullptr, stream);
  launch_gemm<false, false, EPI_NONE>(h_, g_B, g_, M, C_, 128, nullptr, nullptr, nullptr, nullptr, stream);

  // kk prep (z, bb, final k in place)
  {
    dim3 grid((B_ * T_ * H_) / 4), blk(256);
    hipLaunchKernelGGL(kkprep_k, grid, blk, 0, stream, kbuf, a_, k_k, k_a,
                       kbuf, z_, bb_);
  }

  // recurrence -> y (stored in a_ slot; a is dead now)
  {
    dim3 grid(B_ * H_ * 4), blk(64);
    hipLaunchKernelGGL(wkv7_k, grid, blk, 0, stream, r_, dec_, kbuf, vbuf, z_,
                       bb_, a_);
  }

  // groupnorm + rk-term + gate -> ym (stored in dec_ slot; decay dead)
  {
    dim3 grid((B_ * T_ * H_) / 4), blk(256);
    hipLaunchKernelGGL(gn_k, grid, blk, 0, stream, a_, r_, kbuf, vbuf, g_, r_k,
                       ln_w, ln_b, dec_);
  }

  // output projection
  launch_gemm<false, true, EPI_NONE>(dec_, W_o, out, M, C_, C_, nullptr, nullptr, nullptr, nullptr, stream);

  // v_first passthrough (LAYER_ID=1)
  {
    const int n4 = (int)(S / 4);
    dim3 grid((n4 + 255) / 256), blk(256);
    hipLaunchKernelGGL(copy4_k, grid, blk, 0, stream, (const float4*)v_first,
                       (float4*)(out + S), n4);
  }
}

// Round 2
// 2498.808 us; speedup vs baseline: 1.6426x; 1.6426x over previous
//
#include <hip/hip_runtime.h>
#include <hip/hip_bf16.h>
#include <math.h>

// RWKV-7 TimeMix, fp32. R2: latency-optimized wkv7 recurrence.
// B=4 T=2048 C=768 H=12 N=64, LAYER_ID=1 (v_first passes through).
//
// Workspace layout (floats): 8 slots of B*T*C + 1 hidden of B*T*128 ≈ 196 MB.

#define B_  4
#define T_  2048
#define C_  768
#define H_  12
#define NH_ 64

static __device__ __forceinline__ float wave_sum64(float v) {
#pragma unroll
  for (int m = 32; m > 0; m >>= 1) v += __shfl_xor(v, m);
  return v;
}

// ---------------- GEMM ----------------
// C[M,N] = act( A'[M,K] @ B'[K,N] ), A' optionally time-mixed x, B either
// (K,N) row-major (BT=false) or (N,K) row-major i.e. A@W^T (BT=true).
enum { EPI_NONE = 0, EPI_TANH, EPI_WDECAY, EPI_SIGBIAS, EPI_SIGMOID, EPI_VMIX };

template <bool MIX, bool BT, int EPI>
__global__ __launch_bounds__(256) void gemm_k(
    const float* __restrict__ A, const float* __restrict__ Bm,
    float* __restrict__ Cc, int M, int N, int K,
    const float* __restrict__ lam, const float* __restrict__ bias,
    const float* __restrict__ ex1, const float* __restrict__ ex2) {
  __shared__ float As[64][20];
  __shared__ float Bs[64][20];
  const int tid = threadIdx.x;
  const int n0 = blockIdx.x * 64;
  const int m0 = blockIdx.y * 64;
  const int tx = tid & 15, ty = tid >> 4;

  float acc[4][4];
#pragma unroll
  for (int i = 0; i < 4; i++)
#pragma unroll
    for (int j = 0; j < 4; j++) acc[i][j] = 0.f;

  const int lm = tid >> 2;          // 0..63
  const int lk4 = (tid & 3) * 4;    // 0,4,8,12

  for (int k0 = 0; k0 < K; k0 += 16) {
    // ---- A tile (64 x 16) ----
    {
      const int gm = m0 + lm;
      const float* ap = A + (size_t)gm * K + k0 + lk4;
      float4 xa = *(const float4*)ap;
      if (MIX) {
        float4 xp = make_float4(0.f, 0.f, 0.f, 0.f);
        if ((gm % T_) != 0) xp = *(const float4*)(ap - K);
        const float4 l4 = *(const float4*)(lam + k0 + lk4);
        xa.x += (xp.x - xa.x) * l4.x;
        xa.y += (xp.y - xa.y) * l4.y;
        xa.z += (xp.z - xa.z) * l4.z;
        xa.w += (xp.w - xa.w) * l4.w;
      }
      *(float4*)&As[lm][lk4] = xa;
    }
    // ---- B tile (64 n x 16 k) ----
    if (BT) {
      const int gn = n0 + lm;
      const float4 bv = *(const float4*)(Bm + (size_t)gn * K + k0 + lk4);
      *(float4*)&Bs[lm][lk4] = bv;
    } else {
      const int kl = tid >> 4;        // 0..15
      const int nl = (tid & 15) * 4;  // 0..60
      const float4 bv = *(const float4*)(Bm + (size_t)(k0 + kl) * N + n0 + nl);
      Bs[nl + 0][kl] = bv.x;
      Bs[nl + 1][kl] = bv.y;
      Bs[nl + 2][kl] = bv.z;
      Bs[nl + 3][kl] = bv.w;
    }
    __syncthreads();

#pragma unroll
    for (int kb = 0; kb < 16; kb += 4) {
      float a4[4][4], b4[4][4];
#pragma unroll
      for (int i = 0; i < 4; i++) {
        const float4 t = *(const float4*)&As[ty * 4 + i][kb];
        a4[i][0] = t.x; a4[i][1] = t.y; a4[i][2] = t.z; a4[i][3] = t.w;
      }
#pragma unroll
      for (int j = 0; j < 4; j++) {
        const float4 t = *(const float4*)&Bs[tx * 4 + j][kb];
        b4[j][0] = t.x; b4[j][1] = t.y; b4[j][2] = t.z; b4[j][3] = t.w;
      }
#pragma unroll
      for (int u = 0; u < 4; u++)
#pragma unroll
        for (int i = 0; i < 4; i++)
#pragma unroll
          for (int j = 0; j < 4; j++)
            acc[i][j] = fmaf(a4[i][u], b4[j][u], acc[i][j]);
    }
    __syncthreads();
  }

  // ---- epilogue + store ----
#pragma unroll
  for (int i = 0; i < 4; i++) {
    const int gm = m0 + ty * 4 + i;
    float res[4];
#pragma unroll
    for (int j = 0; j < 4; j++) {
      const int n = n0 + tx * 4 + j;
      float val = acc[i][j];
      if (EPI == EPI_TANH) {
        val = tanhf(val);
      } else if (EPI == EPI_WDECAY) {
        const float u = bias[n] + val;
        const float sig = 1.f / (1.f + expf(-u));
        val = expf(-0.60653065971263342f * sig);
      } else if (EPI == EPI_SIGBIAS) {
        const float u = bias[n] + val;
        val = 1.f / (1.f + expf(-u));
      } else if (EPI == EPI_SIGMOID) {
        val = 1.f / (1.f + expf(-val));
      } else if (EPI == EPI_VMIX) {
        const float u = bias[n] + val;
        const float sg = 1.f / (1.f + expf(-u));
        const size_t off = (size_t)gm * N + n;
        const float v0v = ex1[off];
        const float vf = ex2[off];
        val = v0v + (vf - v0v) * sg;
      }
      res[j] = val;
    }
    *(float4*)(Cc + (size_t)gm * N + n0 + tx * 4) =
        make_float4(res[0], res[1], res[2], res[3]);
  }
}

// ---------------- kk prep ----------------
__global__ __launch_bounds__(256) void kkprep_k(
    const float* __restrict__ k0, const float* __restrict__ a,
    const float* __restrict__ k_k, const float* __restrict__ k_a,
    float* __restrict__ kout, float* __restrict__ z, float* __restrict__ bb) {
  const int wid = threadIdx.x >> 6;
  const int lane = threadIdx.x & 63;
  const size_t hid = (size_t)blockIdx.x * 4 + wid;  // (b*T+t)*H + h
  const int h = (int)(hid % H_);
  const size_t idx = hid * 64 + lane;
  const int c = h * 64 + lane;
  const float kv = k0[idx];
  const float av = a[idx];
  const float kk = kv * k_k[c];
  const float ss = wave_sum64(kk * kk);
  const float denom = fmaxf(sqrtf(ss), 1e-12f);
  const float kkn = kk / denom;
  z[idx] = -kkn;
  bb[idx] = kkn * av;
  kout[idx] = kv * (1.f + (av - 1.f) * k_a[c]);
}

// ---------------- WKV-7 recurrence ----------------
// R2: 768 blocks (B*H*16) of 64 threads; block = 4 rows of one (b,h).
// Thread (rr=tid>>4, l=tid&15): row rg*4+rr, cols l*4..l*4+3.
// Software prefetch of step t+1's vectors overlaps step t's dependent chain.
__global__ __launch_bounds__(64) void wkv7_k(
    const float* __restrict__ rr, const float* __restrict__ dd,
    const float* __restrict__ kk, const float* __restrict__ vv,
    const float* __restrict__ zz, const float* __restrict__ bbv,
    float* __restrict__ yy) {
  const int blk = blockIdx.x;
  const int bh = blk >> 4, rg = blk & 15;
  const int b = bh / H_, h = bh % H_;
  const int tid = threadIdx.x;
  const int l16 = tid & 15;
  const int row = rg * 4 + (tid >> 4);
  const int cb = l16 * 4;

  float S0 = 0.f, S1 = 0.f, S2 = 0.f, S3 = 0.f;

  size_t base = ((size_t)b * T_) * C_ + h * 64;
  float4 w4 = *(const float4*)(dd + base + cb);
  float4 z4 = *(const float4*)(zz + base + cb);
  float4 b4 = *(const float4*)(bbv + base + cb);
  float4 k4 = *(const float4*)(kk + base + cb);
  float4 r4 = *(const float4*)(rr + base + cb);
  float vi = vv[base + row];

  for (int t = 0; t < T_; t++) {
    const size_t nbase = base + C_;
    float4 w4n, z4n, b4n, k4n, r4n;
    float vin;
    if (t + 1 < T_) {  // wave-uniform branch; prefetch next step
      w4n = *(const float4*)(dd + nbase + cb);
      z4n = *(const float4*)(zz + nbase + cb);
      b4n = *(const float4*)(bbv + nbase + cb);
      k4n = *(const float4*)(kk + nbase + cb);
      r4n = *(const float4*)(rr + nbase + cb);
      vin = vv[nbase + row];
    }

    // sa = (S z) for this row, reduced over 16 lanes (64 cols)
    float sa = S0 * z4.x;
    sa = fmaf(S1, z4.y, sa);
    sa = fmaf(S2, z4.z, sa);
    sa = fmaf(S3, z4.w, sa);
    sa += __shfl_xor(sa, 1);
    sa += __shfl_xor(sa, 2);
    sa += __shfl_xor(sa, 4);
    sa += __shfl_xor(sa, 8);

    S0 = fmaf(S0, w4.x, fmaf(sa, b4.x, vi * k4.x));
    S1 = fmaf(S1, w4.y, fmaf(sa, b4.y, vi * k4.y));
    S2 = fmaf(S2, w4.z, fmaf(sa, b4.z, vi * k4.z));
    S3 = fmaf(S3, w4.w, fmaf(sa, b4.w, vi * k4.w));

    float yp = S0 * r4.x;
    yp = fmaf(S1, r4.y, yp);
    yp = fmaf(S2, r4.z, yp);
    yp = fmaf(S3, r4.w, yp);
    yp += __shfl_xor(yp, 1);
    yp += __shfl_xor(yp, 2);
    yp += __shfl_xor(yp, 4);
    yp += __shfl_xor(yp, 8);
    if (l16 == 0) yy[base + row] = yp;

    base = nbase;
    w4 = w4n; z4 = z4n; b4 = b4n; k4 = k4n; r4 = r4n; vi = vin;
  }
}

// ---------------- GroupNorm + r_k term + g gating ----------------
__global__ __launch_bounds__(256) void gn_k(
    const float* __restrict__ y, const float* __restrict__ r,
    const float* __restrict__ k, const float* __restrict__ v,
    const float* __restrict__ g, const float* __restrict__ r_k,
    const float* __restrict__ ln_w, const float* __restrict__ ln_b,
    float* __restrict__ ym) {
  const int wid = threadIdx.x >> 6;
  const int lane = threadIdx.x & 63;
  const size_t hid = (size_t)blockIdx.x * 4 + wid;
  const int h = (int)(hid % H_);
  const size_t idx = hid * 64 + lane;
  const int c = h * 64 + lane;

  const float yv = y[idx];
  const float mu = wave_sum64(yv) * (1.f / 64.f);
  const float sq = wave_sum64(yv * yv) * (1.f / 64.f);
  const float var = sq - mu * mu;
  float yn = (yv - mu) * rsqrtf(var + 0.00064f);
  yn = yn * ln_w[c] + ln_b[c];

  const float s = wave_sum64(r[idx] * k[idx] * r_k[c]);
  yn += s * v[idx];
  ym[idx] = yn * g[idx];
}

// ---------------- copy ----------------
__global__ __launch_bounds__(256) void copy4_k(const float4* __restrict__ src,
                                               float4* __restrict__ dst, int n4) {
  const int i = blockIdx.x * blockDim.x + threadIdx.x;
  if (i < n4) dst[i] = src[i];
}

// ---------------- host launcher ----------------
template <bool MIX, bool BT, int EPI>
static void launch_gemm(const float* A, const float* Bm, float* Cc, int M,
                        int N, int K, const float* lam, const float* bias,
                        const float* ex1, const float* ex2, hipStream_t s) {
  dim3 grid(N / 64, M / 64), blk(256);
  hipLaunchKernelGGL((gemm_k<MIX, BT, EPI>), grid, blk, 0, s, A, Bm, Cc, M, N,
                     K, lam, bias, ex1, ex2);
}

extern "C" void kernel_launch(void* const* d_in, const int* in_sizes, int n_in,
                              void* d_out, int out_size, void* d_ws,
                              size_t ws_size, hipStream_t stream) {
  const float* x       = (const float*)d_in[0];
  const float* v_first = (const float*)d_in[1];
  const float* lam_r   = (const float*)d_in[2];
  const float* lam_w   = (const float*)d_in[3];
  const float* lam_k   = (const float*)d_in[4];
  const float* lam_v   = (const float*)d_in[5];
  const float* lam_a   = (const float*)d_in[6];
  const float* lam_g   = (const float*)d_in[7];
  const float* w_miu   = (const float*)d_in[8];
  const float* w_A     = (const float*)d_in[9];
  const float* w_B     = (const float*)d_in[10];
  const float* a_miu   = (const float*)d_in[11];
  const float* a_A     = (const float*)d_in[12];
  const float* a_B     = (const float*)d_in[13];
  const float* v_miu   = (const float*)d_in[14];
  const float* v_A     = (const float*)d_in[15];
  const float* v_B     = (const float*)d_in[16];
  const float* g_A     = (const float*)d_in[17];
  const float* g_B     = (const float*)d_in[18];
  const float* k_k     = (const float*)d_in[19];
  const float* k_a     = (const float*)d_in[20];
  const float* r_k     = (const float*)d_in[21];
  const float* W_r     = (const float*)d_in[22];
  const float* W_k     = (const float*)d_in[23];
  const float* W_v     = (const float*)d_in[24];
  const float* W_o     = (const float*)d_in[25];
  const float* ln_w    = (const float*)d_in[26];
  const float* ln_b    = (const float*)d_in[27];

  const int M = B_ * T_;           // 8192
  const size_t S = (size_t)M * C_; // 6291456

  float* ws   = (float*)d_ws;
  float* r_   = ws + 0 * S;
  float* kbuf = ws + 1 * S;
  float* vbuf = ws + 2 * S;
  float* dec_ = ws + 3 * S;  // decay; reused as ym after recurrence
  float* a_   = ws + 4 * S;  // a; reused as y after kkprep
  float* g_   = ws + 5 * S;
  float* z_   = ws + 6 * S;
  float* bb_  = ws + 7 * S;
  float* h_   = ws + 8 * S;  // hidden, up to M*128
  float* out  = (float*)d_out;

  // big projections (fused time-mix on A load)
  launch_gemm<true, true, EPI_NONE>(x, W_r, r_, M, C_, C_, lam_r, nullptr, nullptr, nullptr, stream);
  launch_gemm<true, true, EPI_NONE>(x, W_k, kbuf, M, C_, C_, lam_k, nullptr, nullptr, nullptr, stream);
  launch_gemm<true, true, EPI_NONE>(x, W_v, vbuf, M, C_, C_, lam_v, nullptr, nullptr, nullptr, stream);

  // v low-rank residual gate (uses v0 = vbuf, writes vbuf in place)
  launch_gemm<false, false, EPI_NONE>(vbuf, v_A, h_, M, 64, C_, nullptr, nullptr, nullptr, nullptr, stream);
  launch_gemm<false, false, EPI_VMIX>(h_, v_B, vbuf, M, C_, 64, nullptr, v_miu, vbuf, v_first, stream);

  // decay path
  launch_gemm<true, false, EPI_TANH>(x, w_A, h_, M, 64, C_, lam_w, nullptr, nullptr, nullptr, stream);
  launch_gemm<false, false, EPI_WDECAY>(h_, w_B, dec_, M, C_, 64, nullptr, w_miu, nullptr, nullptr, stream);

  // a path
  launch_gemm<true, false, EPI_NONE>(x, a_A, h_, M, 64, C_, lam_a, nullptr, nullptr, nullptr, stream);
  launch_gemm<false, false, EPI_SIGBIAS>(h_, a_B, a_, M, C_, 64, nullptr, a_miu, nullptr, nullptr, stream);

  // g path
  launch_gemm<true, false, EPI_SIGMOID>(x, g_A, h_, M, 128, C_, lam_g, nullptr, nullptr, nullptr, stream);
  launch_gemm<false, false, EPI_NONE>(h_, g_B, g_, M, C_, 128, nullptr, nullptr, nullptr, nullptr, stream);

  // kk prep (z, bb, final k in place)
  {
    dim3 grid((B_ * T_ * H_) / 4), blk(256);
    hipLaunchKernelGGL(kkprep_k, grid, blk, 0, stream, kbuf, a_, k_k, k_a,
                       kbuf, z_, bb_);
  }

  // recurrence -> y (stored in a_ slot; a is dead now)
  {
    dim3 grid(B_ * H_ * 16), blk(64);
    hipLaunchKernelGGL(wkv7_k, grid, blk, 0, stream, r_, dec_, kbuf, vbuf, z_,
                       bb_, a_);
  }

  // groupnorm + rk-term + gate -> ym (stored in dec_ slot; decay dead)
  {
    dim3 grid((B_ * T_ * H_) / 4), blk(256);
    hipLaunchKernelGGL(gn_k, grid, blk, 0, stream, a_, r_, kbuf, vbuf, g_, r_k,
                       ln_w, ln_b, dec_);
  }

  // output projection
  launch_gemm<false, true, EPI_NONE>(dec_, W_o, out, M, C_, C_, nullptr, nullptr, nullptr, nullptr, stream);

  // v_first passthrough (LAYER_ID=1)
  {
    const int n4 = (int)(S / 4);
    dim3 grid((n4 + 255) / 256), blk(256);
    hipLaunchKernelGGL(copy4_k, grid, blk, 0, stream, (const float4*)v_first,
                       (float4*)(out + S), n4);
  }
}

// Round 3
// 1618.950 us; speedup vs baseline: 2.5353x; 1.5435x over previous
//
#include <hip/hip_runtime.h>
#include <hip/hip_bf16.h>
#include <math.h>

// RWKV-7 TimeMix. R3: deep-prefetch wkv7 + bf16-MFMA big GEMMs.
// B=4 T=2048 C=768 H=12 N=64, LAYER_ID=1.

#define B_  4
#define T_  2048
#define C_  768
#define H_  12

typedef __attribute__((ext_vector_type(8))) short bf16x8;
typedef __attribute__((ext_vector_type(4))) float f32x4;

#define GLD16(gsrc, ldst)                                                     \
  __builtin_amdgcn_global_load_lds(                                           \
      (const __attribute__((address_space(1))) void*)(gsrc),                  \
      (__attribute__((address_space(3))) void*)(ldst), 16, 0, 0)

static __device__ __forceinline__ float wave_sum64(float v) {
#pragma unroll
  for (int m = 32; m > 0; m >>= 1) v += __shfl_xor(v, m);
  return v;
}

static __device__ __forceinline__ short bf16b(float f) {
  __hip_bfloat16 h = __float2bfloat16(f);
  return *reinterpret_cast<short*>(&h);
}

// ---------------- bf16 MFMA GEMM ----------------
// C[M,N] = A[M,K](bf16) @ Bw[N,K](bf16)^T, fp32 out. 128x128 tile, BK=32.
// 4 waves in 2x2, each wave 64x64 via 4x4 grid of 16x16x32 MFMAs.
__global__ __launch_bounds__(256) void gemm_bf16_k(
    const short* __restrict__ A, const short* __restrict__ Bw,
    float* __restrict__ C, int M, int N, int K) {
  __shared__ short As[128 * 32];
  __shared__ short Bs[128 * 32];
  const int tid = threadIdx.x;
  const int wave = tid >> 6, lane = tid & 63;
  const int m0 = blockIdx.y * 128, n0 = blockIdx.x * 128;
  const int wm = (wave >> 1) * 64, wn = (wave & 1) * 64;
  const int fr = lane & 15, fk = (lane >> 4) * 8;

  f32x4 acc[4][4];
#pragma unroll
  for (int i = 0; i < 4; i++)
#pragma unroll
    for (int j = 0; j < 4; j++) acc[i][j] = (f32x4){0.f, 0.f, 0.f, 0.f};

  // staging map: thread t -> LDS short-offset 8*t == row (t>>2), col (t&3)*8
  const int srow = tid >> 2, scol = (tid & 3) * 8;
  const short* gA = A + (size_t)(m0 + srow) * K + scol;
  const short* gB = Bw + (size_t)(n0 + srow) * K + scol;
  short* lA0 = &As[wave * 512];
  short* lA1 = &As[2048 + wave * 512];
  short* lB0 = &Bs[wave * 512];
  short* lB1 = &Bs[2048 + wave * 512];

  for (int k0 = 0; k0 < K; k0 += 32) {
    GLD16(gA + k0, lA0);
    GLD16(gA + (size_t)64 * K + k0, lA1);
    GLD16(gB + k0, lB0);
    GLD16(gB + (size_t)64 * K + k0, lB1);
    __syncthreads();

    bf16x8 af[4], bf[4];
#pragma unroll
    for (int i = 0; i < 4; i++)
      af[i] = *(const bf16x8*)&As[(wm + i * 16 + fr) * 32 + fk];
#pragma unroll
    for (int j = 0; j < 4; j++)
      bf[j] = *(const bf16x8*)&Bs[(wn + j * 16 + fr) * 32 + fk];
#pragma unroll
    for (int i = 0; i < 4; i++)
#pragma unroll
      for (int j = 0; j < 4; j++)
        acc[i][j] =
            __builtin_amdgcn_mfma_f32_16x16x32_bf16(af[i], bf[j], acc[i][j], 0, 0, 0);
    __syncthreads();
  }

  // C/D layout: col = lane&15, row = (lane>>4)*4 + reg  [m89/m91 verified]
#pragma unroll
  for (int i = 0; i < 4; i++) {
    const int gm = m0 + wm + i * 16 + (lane >> 4) * 4;
#pragma unroll
    for (int j = 0; j < 4; j++) {
      const int gn = n0 + wn + j * 16 + fr;
#pragma unroll
      for (int rix = 0; rix < 4; rix++)
        C[(size_t)(gm + rix) * N + gn] = acc[i][j][rix];
    }
  }
}

// ---------------- fp32 GEMM (small paths) ----------------
enum { EPI_NONE = 0, EPI_TANH, EPI_WDECAY, EPI_SIGBIAS, EPI_SIGMOID, EPI_VMIX };

template <bool MIX, bool BT, int EPI>
__global__ __launch_bounds__(256) void gemm_k(
    const float* __restrict__ A, const float* __restrict__ Bm,
    float* __restrict__ Cc, int M, int N, int K,
    const float* __restrict__ lam, const float* __restrict__ bias,
    const float* __restrict__ ex1, const float* __restrict__ ex2) {
  __shared__ float As[64][20];
  __shared__ float Bs[64][20];
  const int tid = threadIdx.x;
  const int n0 = blockIdx.x * 64;
  const int m0 = blockIdx.y * 64;
  const int tx = tid & 15, ty = tid >> 4;

  float acc[4][4];
#pragma unroll
  for (int i = 0; i < 4; i++)
#pragma unroll
    for (int j = 0; j < 4; j++) acc[i][j] = 0.f;

  const int lm = tid >> 2;
  const int lk4 = (tid & 3) * 4;

  for (int k0 = 0; k0 < K; k0 += 16) {
    {
      const int gm = m0 + lm;
      const float* ap = A + (size_t)gm * K + k0 + lk4;
      float4 xa = *(const float4*)ap;
      if (MIX) {
        float4 xp = make_float4(0.f, 0.f, 0.f, 0.f);
        if ((gm % T_) != 0) xp = *(const float4*)(ap - K);
        const float4 l4 = *(const float4*)(lam + k0 + lk4);
        xa.x += (xp.x - xa.x) * l4.x;
        xa.y += (xp.y - xa.y) * l4.y;
        xa.z += (xp.z - xa.z) * l4.z;
        xa.w += (xp.w - xa.w) * l4.w;
      }
      *(float4*)&As[lm][lk4] = xa;
    }
    if (BT) {
      const int gn = n0 + lm;
      const float4 bv = *(const float4*)(Bm + (size_t)gn * K + k0 + lk4);
      *(float4*)&Bs[lm][lk4] = bv;
    } else {
      const int kl = tid >> 4;
      const int nl = (tid & 15) * 4;
      const float4 bv = *(const float4*)(Bm + (size_t)(k0 + kl) * N + n0 + nl);
      Bs[nl + 0][kl] = bv.x;
      Bs[nl + 1][kl] = bv.y;
      Bs[nl + 2][kl] = bv.z;
      Bs[nl + 3][kl] = bv.w;
    }
    __syncthreads();

#pragma unroll
    for (int kb = 0; kb < 16; kb += 4) {
      float a4[4][4], b4[4][4];
#pragma unroll
      for (int i = 0; i < 4; i++) {
        const float4 t = *(const float4*)&As[ty * 4 + i][kb];
        a4[i][0] = t.x; a4[i][1] = t.y; a4[i][2] = t.z; a4[i][3] = t.w;
      }
#pragma unroll
      for (int j = 0; j < 4; j++) {
        const float4 t = *(const float4*)&Bs[tx * 4 + j][kb];
        b4[j][0] = t.x; b4[j][1] = t.y; b4[j][2] = t.z; b4[j][3] = t.w;
      }
#pragma unroll
      for (int u = 0; u < 4; u++)
#pragma unroll
        for (int i = 0; i < 4; i++)
#pragma unroll
          for (int j = 0; j < 4; j++)
            acc[i][j] = fmaf(a4[i][u], b4[j][u], acc[i][j]);
    }
    __syncthreads();
  }

#pragma unroll
  for (int i = 0; i < 4; i++) {
    const int gm = m0 + ty * 4 + i;
    float res[4];
#pragma unroll
    for (int j = 0; j < 4; j++) {
      const int n = n0 + tx * 4 + j;
      float val = acc[i][j];
      if (EPI == EPI_TANH) {
        val = tanhf(val);
      } else if (EPI == EPI_WDECAY) {
        const float u = bias[n] + val;
        const float sig = 1.f / (1.f + expf(-u));
        val = expf(-0.60653065971263342f * sig);
      } else if (EPI == EPI_SIGBIAS) {
        const float u = bias[n] + val;
        val = 1.f / (1.f + expf(-u));
      } else if (EPI == EPI_SIGMOID) {
        val = 1.f / (1.f + expf(-val));
      } else if (EPI == EPI_VMIX) {
        const float u = bias[n] + val;
        const float sg = 1.f / (1.f + expf(-u));
        const size_t off = (size_t)gm * N + n;
        const float v0v = ex1[off];
        const float vf = ex2[off];
        val = v0v + (vf - v0v) * sg;
      }
      res[j] = val;
    }
    *(float4*)(Cc + (size_t)gm * N + n0 + tx * 4) =
        make_float4(res[0], res[1], res[2], res[3]);
  }
}

// ---------------- mix -> bf16 (3 lambdas) ----------------
__global__ __launch_bounds__(256) void mix3_k(
    const float* __restrict__ x, const float* __restrict__ lr,
    const float* __restrict__ lk, const float* __restrict__ lv,
    short* __restrict__ xr, short* __restrict__ xk, short* __restrict__ xv) {
  const int i = blockIdx.x * 256 + threadIdx.x;  // float4 index
  const int c4 = i % (C_ / 4);
  const int gm = i / (C_ / 4);
  const float4 xa = ((const float4*)x)[i];
  float4 xp = make_float4(0.f, 0.f, 0.f, 0.f);
  if ((gm % T_) != 0) xp = ((const float4*)x)[i - C_ / 4];
  const float4 dx = make_float4(xp.x - xa.x, xp.y - xa.y, xp.z - xa.z, xp.w - xa.w);

  const float4 l1 = ((const float4*)lr)[c4];
  const float4 l2 = ((const float4*)lk)[c4];
  const float4 l3 = ((const float4*)lv)[c4];
  short4 o1 = {bf16b(fmaf(dx.x, l1.x, xa.x)), bf16b(fmaf(dx.y, l1.y, xa.y)),
               bf16b(fmaf(dx.z, l1.z, xa.z)), bf16b(fmaf(dx.w, l1.w, xa.w))};
  short4 o2 = {bf16b(fmaf(dx.x, l2.x, xa.x)), bf16b(fmaf(dx.y, l2.y, xa.y)),
               bf16b(fmaf(dx.z, l2.z, xa.z)), bf16b(fmaf(dx.w, l2.w, xa.w))};
  short4 o3 = {bf16b(fmaf(dx.x, l3.x, xa.x)), bf16b(fmaf(dx.y, l3.y, xa.y)),
               bf16b(fmaf(dx.z, l3.z, xa.z)), bf16b(fmaf(dx.w, l3.w, xa.w))};
  ((short4*)xr)[i] = o1;
  ((short4*)xk)[i] = o2;
  ((short4*)xv)[i] = o3;
}

// ---------------- fp32 -> bf16 convert ----------------
__global__ __launch_bounds__(256) void cvtw_k(const float* __restrict__ in,
                                              short* __restrict__ out, int n4) {
  const int i = blockIdx.x * 256 + threadIdx.x;
  if (i >= n4) return;
  const float4 v = ((const float4*)in)[i];
  short4 o = {bf16b(v.x), bf16b(v.y), bf16b(v.z), bf16b(v.w)};
  ((short4*)out)[i] = o;
}

// ---------------- kk prep ----------------
__global__ __launch_bounds__(256) void kkprep_k(
    const float* __restrict__ k0, const float* __restrict__ a,
    const float* __restrict__ k_k, const float* __restrict__ k_a,
    float* __restrict__ kout, float* __restrict__ z, float* __restrict__ bb) {
  const int wid = threadIdx.x >> 6;
  const int lane = threadIdx.x & 63;
  const size_t hid = (size_t)blockIdx.x * 4 + wid;
  const int h = (int)(hid % H_);
  const size_t idx = hid * 64 + lane;
  const int c = h * 64 + lane;
  const float kv = k0[idx];
  const float av = a[idx];
  const float kk = kv * k_k[c];
  const float ss = wave_sum64(kk * kk);
  const float denom = fmaxf(sqrtf(ss), 1e-12f);
  const float kkn = kk / denom;
  z[idx] = -kkn;
  bb[idx] = kkn * av;
  kout[idx] = kv * (1.f + (av - 1.f) * k_a[c]);
}

// ---------------- WKV-7 recurrence, prefetch depth 8 ----------------
// 768 blocks (B*H*16) x 64 threads; wave = 4 rows, 16 lanes/row, 4 cols/lane.
#define PFD 8
__global__ __launch_bounds__(64) void wkv7_k(
    const float* __restrict__ rr, const float* __restrict__ dd,
    const float* __restrict__ kk, const float* __restrict__ vv,
    const float* __restrict__ zz, const float* __restrict__ bbv,
    float* __restrict__ yy) {
  const int blk = blockIdx.x;
  const int bh = blk >> 4, rg = blk & 15;
  const int b = bh / H_, h = bh % H_;
  const int tid = threadIdx.x;
  const int l16 = tid & 15;
  const int row = rg * 4 + (tid >> 4);
  const int cb = l16 * 4;

  float S0 = 0.f, S1 = 0.f, S2 = 0.f, S3 = 0.f;
  const size_t base0 = ((size_t)b * T_) * C_ + h * 64;

  float4 wv[PFD], zv[PFD], bv[PFD], kv[PFD], rv[PFD];
  float vval[PFD];
#pragma unroll
  for (int d = 0; d < PFD; d++) {
    const size_t pb = base0 + (size_t)d * C_;
    wv[d] = *(const float4*)(dd + pb + cb);
    zv[d] = *(const float4*)(zz + pb + cb);
    bv[d] = *(const float4*)(bbv + pb + cb);
    kv[d] = *(const float4*)(kk + pb + cb);
    rv[d] = *(const float4*)(rr + pb + cb);
    vval[d] = vv[pb + row];
  }

  for (int t0 = 0; t0 < T_; t0 += PFD) {
#pragma unroll
    for (int d = 0; d < PFD; d++) {
      const int t = t0 + d;
      const float4 w4 = wv[d], z4 = zv[d], b4 = bv[d], k4 = kv[d], r4 = rv[d];
      const float vi = vval[d];

      // prefetch step t+PFD into slot d (clamped to stay in-bounds)
      const int tp = (t + PFD < T_) ? (t + PFD) : (T_ - 1);
      const size_t pb = base0 + (size_t)tp * C_;
      wv[d] = *(const float4*)(dd + pb + cb);
      zv[d] = *(const float4*)(zz + pb + cb);
      bv[d] = *(const float4*)(bbv + pb + cb);
      kv[d] = *(const float4*)(kk + pb + cb);
      rv[d] = *(const float4*)(rr + pb + cb);
      vval[d] = vv[pb + row];

      float sa = S0 * z4.x;
      sa = fmaf(S1, z4.y, sa);
      sa = fmaf(S2, z4.z, sa);
      sa = fmaf(S3, z4.w, sa);
      sa += __shfl_xor(sa, 1);
      sa += __shfl_xor(sa, 2);
      sa += __shfl_xor(sa, 4);
      sa += __shfl_xor(sa, 8);

      S0 = fmaf(S0, w4.x, fmaf(sa, b4.x, vi * k4.x));
      S1 = fmaf(S1, w4.y, fmaf(sa, b4.y, vi * k4.y));
      S2 = fmaf(S2, w4.z, fmaf(sa, b4.z, vi * k4.z));
      S3 = fmaf(S3, w4.w, fmaf(sa, b4.w, vi * k4.w));

      float yp = S0 * r4.x;
      yp = fmaf(S1, r4.y, yp);
      yp = fmaf(S2, r4.z, yp);
      yp = fmaf(S3, r4.w, yp);
      yp += __shfl_xor(yp, 1);
      yp += __shfl_xor(yp, 2);
      yp += __shfl_xor(yp, 4);
      yp += __shfl_xor(yp, 8);
      if (l16 == 0) yy[base0 + (size_t)t * C_ + row] = yp;
    }
  }
}

// ---------------- GroupNorm + r_k term + g gating -> bf16 ----------------
__global__ __launch_bounds__(256) void gn_k(
    const float* __restrict__ y, const float* __restrict__ r,
    const float* __restrict__ k, const float* __restrict__ v,
    const float* __restrict__ g, const float* __restrict__ r_k,
    const float* __restrict__ ln_w, const float* __restrict__ ln_b,
    short* __restrict__ ymb) {
  const int wid = threadIdx.x >> 6;
  const int lane = threadIdx.x & 63;
  const size_t hid = (size_t)blockIdx.x * 4 + wid;
  const int h = (int)(hid % H_);
  const size_t idx = hid * 64 + lane;
  const int c = h * 64 + lane;

  const float yv = y[idx];
  const float mu = wave_sum64(yv) * (1.f / 64.f);
  const float sq = wave_sum64(yv * yv) * (1.f / 64.f);
  const float var = sq - mu * mu;
  float yn = (yv - mu) * rsqrtf(var + 0.00064f);
  yn = yn * ln_w[c] + ln_b[c];

  const float s = wave_sum64(r[idx] * k[idx] * r_k[c]);
  yn += s * v[idx];
  ymb[idx] = bf16b(yn * g[idx]);
}

// ---------------- copy ----------------
__global__ __launch_bounds__(256) void copy4_k(const float4* __restrict__ src,
                                               float4* __restrict__ dst, int n4) {
  const int i = blockIdx.x * blockDim.x + threadIdx.x;
  if (i < n4) dst[i] = src[i];
}

// ---------------- host launcher ----------------
template <bool MIX, bool BT, int EPI>
static void launch_gemm(const float* A, const float* Bm, float* Cc, int M,
                        int N, int K, const float* lam, const float* bias,
                        const float* ex1, const float* ex2, hipStream_t s) {
  dim3 grid(N / 64, M / 64), blk(256);
  hipLaunchKernelGGL((gemm_k<MIX, BT, EPI>), grid, blk, 0, s, A, Bm, Cc, M, N,
                     K, lam, bias, ex1, ex2);
}

extern "C" void kernel_launch(void* const* d_in, const int* in_sizes, int n_in,
                              void* d_out, int out_size, void* d_ws,
                              size_t ws_size, hipStream_t stream) {
  const float* x       = (const float*)d_in[0];
  const float* v_first = (const float*)d_in[1];
  const float* lam_r   = (const float*)d_in[2];
  const float* lam_w   = (const float*)d_in[3];
  const float* lam_k   = (const float*)d_in[4];
  const float* lam_v   = (const float*)d_in[5];
  const float* lam_a   = (const float*)d_in[6];
  const float* lam_g   = (const float*)d_in[7];
  const float* w_miu   = (const float*)d_in[8];
  const float* w_A     = (const float*)d_in[9];
  const float* w_B     = (const float*)d_in[10];
  const float* a_miu   = (const float*)d_in[11];
  const float* a_A     = (const float*)d_in[12];
  const float* a_B     = (const float*)d_in[13];
  const float* v_miu   = (const float*)d_in[14];
  const float* v_A     = (const float*)d_in[15];
  const float* v_B     = (const float*)d_in[16];
  const float* g_A     = (const float*)d_in[17];
  const float* g_B     = (const float*)d_in[18];
  const float* k_k     = (const float*)d_in[19];
  const float* k_a     = (const float*)d_in[20];
  const float* r_k     = (const float*)d_in[21];
  const float* W_r     = (const float*)d_in[22];
  const float* W_k     = (const float*)d_in[23];
  const float* W_v     = (const float*)d_in[24];
  const float* W_o     = (const float*)d_in[25];
  const float* ln_w    = (const float*)d_in[26];
  const float* ln_b    = (const float*)d_in[27];

  const int M = B_ * T_;            // 8192
  const size_t S = (size_t)M * C_;  // 6291456

  float* ws   = (float*)d_ws;
  float* r_   = ws + 0 * S;
  float* kbuf = ws + 1 * S;
  float* vbuf = ws + 2 * S;
  float* dec_ = ws + 3 * S;
  float* a_   = ws + 4 * S;
  float* g_   = ws + 5 * S;
  float* z_   = ws + 6 * S;
  float* bb_  = ws + 7 * S;
  float* h_   = ws + 8 * S;                       // M*128 floats
  short* wb   = (short*)(h_ + (size_t)M * 128);   // 4 bf16 weight copies
  float* out  = (float*)d_out;

  // bf16 aliases (dead fp32 slots at time of use)
  short* xr  = (short*)dec_;  // consumed before decay written
  short* xk  = (short*)a_;    // consumed before a written
  short* xv  = (short*)g_;    // consumed before g written
  short* ymb = (short*)z_;    // written after z consumed by wkv7
  const int WN = C_ * C_;     // 589824
  short* wrb = wb + 0 * (size_t)WN;
  short* wkb = wb + 1 * (size_t)WN;
  short* wvb = wb + 2 * (size_t)WN;
  short* wob = wb + 3 * (size_t)WN;

  // 1) weights -> bf16
  {
    dim3 blk(256), grid(WN / 4 / 256);
    hipLaunchKernelGGL(cvtw_k, grid, blk, 0, stream, W_r, wrb, WN / 4);
    hipLaunchKernelGGL(cvtw_k, grid, blk, 0, stream, W_k, wkb, WN / 4);
    hipLaunchKernelGGL(cvtw_k, grid, blk, 0, stream, W_v, wvb, WN / 4);
    hipLaunchKernelGGL(cvtw_k, grid, blk, 0, stream, W_o, wob, WN / 4);
  }
  // 2) mixed x -> bf16 (r/k/v lambdas)
  {
    dim3 blk(256), grid((int)(S / 4 / 256));
    hipLaunchKernelGGL(mix3_k, grid, blk, 0, stream, x, lam_r, lam_k, lam_v,
                       xr, xk, xv);
  }
  // 3) big projections via MFMA
  {
    dim3 blk(256), grid(C_ / 128, M / 128);
    hipLaunchKernelGGL(gemm_bf16_k, grid, blk, 0, stream, xr, wrb, r_, M, C_, C_);
    hipLaunchKernelGGL(gemm_bf16_k, grid, blk, 0, stream, xk, wkb, kbuf, M, C_, C_);
    hipLaunchKernelGGL(gemm_bf16_k, grid, blk, 0, stream, xv, wvb, vbuf, M, C_, C_);
  }
  // 4) v low-rank residual gate
  launch_gemm<false, false, EPI_NONE>(vbuf, v_A, h_, M, 64, C_, nullptr, nullptr, nullptr, nullptr, stream);
  launch_gemm<false, false, EPI_VMIX>(h_, v_B, vbuf, M, C_, 64, nullptr, v_miu, vbuf, v_first, stream);
  // 5) decay / a / g paths (fp32, mix fused)
  launch_gemm<true, false, EPI_TANH>(x, w_A, h_, M, 64, C_, lam_w, nullptr, nullptr, nullptr, stream);
  launch_gemm<false, false, EPI_WDECAY>(h_, w_B, dec_, M, C_, 64, nullptr, w_miu, nullptr, nullptr, stream);
  launch_gemm<true, false, EPI_NONE>(x, a_A, h_, M, 64, C_, lam_a, nullptr, nullptr, nullptr, stream);
  launch_gemm<false, false, EPI_SIGBIAS>(h_, a_B, a_, M, C_, 64, nullptr, a_miu, nullptr, nullptr, stream);
  launch_gemm<true, false, EPI_SIGMOID>(x, g_A, h_, M, 128, C_, lam_g, nullptr, nullptr, nullptr, stream);
  launch_gemm<false, false, EPI_NONE>(h_, g_B, g_, M, C_, 128, nullptr, nullptr, nullptr, nullptr, stream);
  // 6) kk prep
  {
    dim3 grid((B_ * T_ * H_) / 4), blk(256);
    hipLaunchKernelGGL(kkprep_k, grid, blk, 0, stream, kbuf, a_, k_k, k_a,
                       kbuf, z_, bb_);
  }
  // 7) recurrence -> y (a_ slot)
  {
    dim3 grid(B_ * H_ * 16), blk(64);
    hipLaunchKernelGGL(wkv7_k, grid, blk, 0, stream, r_, dec_, kbuf, vbuf, z_,
                       bb_, a_);
  }
  // 8) groupnorm + rk-term + gate -> ymb (bf16, z_ slot)
  {
    dim3 grid((B_ * T_ * H_) / 4), blk(256);
    hipLaunchKernelGGL(gn_k, grid, blk, 0, stream, a_, r_, kbuf, vbuf, g_, r_k,
                       ln_w, ln_b, ymb);
  }
  // 9) output projection via MFMA
  {
    dim3 blk(256), grid(C_ / 128, M / 128);
    hipLaunchKernelGGL(gemm_bf16_k, grid, blk, 0, stream, ymb, wob, out, M, C_, C_);
  }
  // 10) v_first passthrough
  {
    const int n4 = (int)(S / 4);
    dim3 grid((n4 + 255) / 256), blk(256);
    hipLaunchKernelGGL(copy4_k, grid, blk, 0, stream, (const float4*)v_first,
                       (float4*)(out + S), n4);
  }
}